// Round 5
// baseline (2302.970 us; speedup 1.0000x reference)
//
#include <hip/hip_runtime.h>
#include <stdint.h>

#define T_TOK 1024
#define HD 2880
#define ID 2880
#define NE 16
#define NTOP 4
#define SZ ((size_t)HD * ID)   // elems per weight matrix

#define BM 128
#define BN 64
#define NKT (HD / 64)          // 45
#define NIB (ID / BN)          // 45
#define NB1 (NIB * 8)          // 360 blocks per expert (8 m-blocks, early-exit)

typedef short bf16x8 __attribute__((ext_vector_type(8)));
typedef float f32x4 __attribute__((ext_vector_type(4)));

__device__ __forceinline__ uint4 pack8f(const float* v) {
    union { __bf16 b[8]; uint4 q; } p;
#pragma unroll
    for (int j = 0; j < 8; j++) p.b[j] = (__bf16)v[j];
    return p.q;
}
__device__ __forceinline__ unsigned short bf16bits(float f) {
    union { __bf16 b[2]; unsigned short u[2]; } p;
    p.b[0] = (__bf16)f;
    return p.u[0];
}

// ---------------- init ----------------
__global__ __launch_bounds__(256) void k_init(float* __restrict__ out, int* __restrict__ cnt) {
    int i = blockIdx.x * 256 + threadIdx.x;
    ((float4*)out)[i] = make_float4(0.f, 0.f, 0.f, 0.f);
    if (blockIdx.x == 0 && threadIdx.x < NE) cnt[threadIdx.x] = 0;
}

// ---------------- x -> bf16 ----------------
__global__ __launch_bounds__(256) void k_xbf(const float* __restrict__ x, unsigned short* __restrict__ xbf) {
    const size_t i = (size_t)blockIdx.x * 256 + threadIdx.x;
    float v[8];
    float4 a = ((const float4*)x)[i * 2];
    float4 b = ((const float4*)x)[i * 2 + 1];
    v[0] = a.x; v[1] = a.y; v[2] = a.z; v[3] = a.w;
    v[4] = b.x; v[5] = b.y; v[6] = b.z; v[7] = b.w;
    ((uint4*)xbf)[i] = pack8f(v);
}

// ---------------- router ----------------
__global__ __launch_bounds__(256) void k_router(
    const float* __restrict__ x, const float* __restrict__ rw, const float* __restrict__ rb,
    float* __restrict__ topw, int* __restrict__ cnt, int* __restrict__ list)
{
    const int t = blockIdx.x;
    const int tid = threadIdx.x;
    float acc[NE];
#pragma unroll
    for (int e = 0; e < NE; e++) acc[e] = 0.f;
    for (int c = tid; c < HD; c += 256) {
        float xv = x[(size_t)t * HD + c];
#pragma unroll
        for (int e = 0; e < NE; e++) acc[e] += xv * rw[(size_t)e * HD + c];
    }
    __shared__ float red[4][NE];
    const int lane = tid & 63, wv = tid >> 6;
#pragma unroll
    for (int e = 0; e < NE; e++) {
        float v = acc[e];
#pragma unroll
        for (int off = 32; off > 0; off >>= 1) v += __shfl_down(v, off, 64);
        if (lane == 0) red[wv][e] = v;
    }
    __syncthreads();
    if (tid == 0) {
        float p[NE];
        float mx = -1e30f;
        for (int e = 0; e < NE; e++) {
            float v = red[0][e] + red[1][e] + red[2][e] + red[3][e] + rb[e];
            p[e] = v; mx = fmaxf(mx, v);
        }
        for (int e = 0; e < NE; e++) p[e] = expf(p[e] - mx);
        int sel[NTOP]; float pw[NTOP]; float ssum = 0.f;
        for (int k = 0; k < NTOP; k++) {
            float best = -1.f; int bi = 0;
            for (int e = 0; e < NE; e++)
                if (p[e] > best) { best = p[e]; bi = e; }
            sel[k] = bi; pw[k] = best; ssum += best; p[bi] = -2.f;
        }
        for (int k = 0; k < NTOP; k++) {
            topw[t * NTOP + k] = pw[k] / ssum;
            int e = sel[k];
            int pos = atomicAdd(&cnt[e], 1);
            list[e * T_TOK + pos] = t * NTOP + k;
        }
    }
}

// ---------------- prefix scan ----------------
__global__ void k_scan(const int* __restrict__ cnt, int* __restrict__ offs) {
    if (threadIdx.x == 0 && blockIdx.x == 0) {
        int s = 0;
        for (int e = 0; e < NE; e++) { offs[e] = s; s += cnt[e]; }
        offs[NE] = s;
    }
}

// ---------------- transpose+convert: src fp32 [2880 k][2880 c] -> dst bf16 [c][k] ----------------
__device__ __forceinline__ void tr_tile(const float* __restrict__ src, unsigned short* __restrict__ dst) {
    __shared__ float s[64][68];
    const int it = blockIdx.x, kt = blockIdx.y;
    const int r = threadIdx.x >> 2, c4 = threadIdx.x & 3;
    const float* p = src + (size_t)(kt * 64 + r) * ID + it * 64 + c4 * 16;
    float4 v0 = ((const float4*)p)[0], v1 = ((const float4*)p)[1];
    float4 v2 = ((const float4*)p)[2], v3 = ((const float4*)p)[3];
    *(float4*)&s[r][c4 * 16 + 0]  = v0;
    *(float4*)&s[r][c4 * 16 + 4]  = v1;
    *(float4*)&s[r][c4 * 16 + 8]  = v2;
    *(float4*)&s[r][c4 * 16 + 12] = v3;
    __syncthreads();
    const int il = threadIdx.x >> 2, kseg = threadIdx.x & 3;
    float v[16];
#pragma unroll
    for (int j = 0; j < 16; j++) v[j] = s[kseg * 16 + j][il];
    unsigned short* q = dst + (size_t)(it * 64 + il) * HD + kt * 64 + kseg * 16;
    *(uint4*)q = pack8f(v);
    *(uint4*)(q + 8) = pack8f(v + 8);
}

__global__ __launch_bounds__(256) void k_trgu(const float* __restrict__ wg, const float* __restrict__ wu,
                                              int e0, unsigned short* __restrict__ dst) {
    const int j = blockIdx.z;   // slot: expert (j>>1), j&1 ? up : gate
    const float* src = ((j & 1) ? wu : wg) + (size_t)(e0 + (j >> 1)) * SZ;
    tr_tile(src, dst + (size_t)j * SZ);
}

__global__ __launch_bounds__(256) void k_trd(const float* __restrict__ wd, int e0,
                                             unsigned short* __restrict__ dst) {
    tr_tile(wd + (size_t)(e0 + blockIdx.z) * SZ, dst + (size_t)blockIdx.z * SZ);
}

// ---------------- GEMM1: zero LDS, zero barriers, pure stream ----------------
__global__ __launch_bounds__(512, 4) void k_gemm1(
    const unsigned short* __restrict__ xbf,
    const unsigned short* __restrict__ wt,    // [2*ne][2880][2880] bf16 transposed
    const float* __restrict__ bg, const float* __restrict__ bu,
    const int* __restrict__ cnt, const int* __restrict__ offs,
    const int* __restrict__ list, int e0,
    unsigned short* __restrict__ act)
{
    const int le = blockIdx.z, e = e0 + le;
    const int lin = blockIdx.x;                        // 360
    const int l = (lin & 7) * (NB1 / 8) + (lin >> 3);  // XCD swizzle: same-panel blocks co-XCD
    const int it = l >> 3, mblk = l & 7;

    const int count = cnt[e];
    const int m0 = mblk * BM;
    if (m0 >= count) return;
    const int mcount = min(BM, count - m0);
    const int i0 = it * BN;

    const int tid = threadIdx.x;
    const int lane = tid & 63, wid = tid >> 6;
    const int wm = wid >> 1, wn = wid & 1;
    const int lr = lane & 15, lk = lane >> 4;

    const unsigned short* wtg = wt + (size_t)(2 * le) * SZ;
    const unsigned short* wtu = wt + (size_t)(2 * le + 1) * SZ;

    const int r0 = m0 + min(wm * 32 + lr, mcount - 1);
    const int r1 = m0 + min(wm * 32 + 16 + lr, mcount - 1);
    const unsigned short* arow0 = xbf + (size_t)(list[e * T_TOK + r0] >> 2) * HD;
    const unsigned short* arow1 = xbf + (size_t)(list[e * T_TOK + r1] >> 2) * HD;
    const unsigned short* g0 = wtg + (size_t)(i0 + wn * 32 + lr) * HD;
    const unsigned short* g1 = wtg + (size_t)(i0 + wn * 32 + 16 + lr) * HD;
    const unsigned short* u0 = wtu + (size_t)(i0 + wn * 32 + lr) * HD;
    const unsigned short* u1 = wtu + (size_t)(i0 + wn * 32 + 16 + lr) * HD;

    f32x4 accG[2][2], accU[2][2];
#pragma unroll
    for (int mb = 0; mb < 2; mb++)
#pragma unroll
        for (int cb = 0; cb < 2; cb++) {
            accG[mb][cb] = (f32x4){0.f, 0.f, 0.f, 0.f};
            accU[mb][cb] = (f32x4){0.f, 0.f, 0.f, 0.f};
        }

#pragma unroll 3
    for (int kt = 0; kt < NKT; kt++) {
        bf16x8 af[2][2], gf[2][2], uf[2][2];
#pragma unroll
        for (int ks = 0; ks < 2; ks++) {
            const int koff = kt * 64 + (ks * 4 + lk) * 8;
            af[ks][0] = *(const bf16x8*)(arow0 + koff);
            af[ks][1] = *(const bf16x8*)(arow1 + koff);
            gf[ks][0] = *(const bf16x8*)(g0 + koff);
            gf[ks][1] = *(const bf16x8*)(g1 + koff);
            uf[ks][0] = *(const bf16x8*)(u0 + koff);
            uf[ks][1] = *(const bf16x8*)(u1 + koff);
        }
#pragma unroll
        for (int ks = 0; ks < 2; ks++)
#pragma unroll
            for (int cb = 0; cb < 2; cb++) {
                accG[0][cb] = __builtin_amdgcn_mfma_f32_16x16x32_bf16(af[ks][0], gf[ks][cb], accG[0][cb], 0, 0, 0);
                accG[1][cb] = __builtin_amdgcn_mfma_f32_16x16x32_bf16(af[ks][1], gf[ks][cb], accG[1][cb], 0, 0, 0);
                accU[0][cb] = __builtin_amdgcn_mfma_f32_16x16x32_bf16(af[ks][0], uf[ks][cb], accU[0][cb], 0, 0, 0);
                accU[1][cb] = __builtin_amdgcn_mfma_f32_16x16x32_bf16(af[ks][1], uf[ks][cb], accU[1][cb], 0, 0, 0);
            }
    }

    const int gbase = offs[e] + m0;
#pragma unroll
    for (int mb = 0; mb < 2; mb++)
#pragma unroll
        for (int cb = 0; cb < 2; cb++) {
            const int col = i0 + wn * 32 + cb * 16 + lr;
            const float bgv = bg[e * ID + col];
            const float buv = bu[e * ID + col];
#pragma unroll
            for (int q = 0; q < 4; q++) {
                const int r = wm * 32 + mb * 16 + lk * 4 + q;
                if (r < mcount) {
                    float gv = fminf(accG[mb][cb][q] + bgv, 7.0f);
                    float uv = fminf(fmaxf(accU[mb][cb][q] + buv, -7.0f), 7.0f);
                    float av = (uv + 1.0f) * (gv / (1.0f + __expf(-1.702f * gv)));
                    act[(size_t)(gbase + r) * ID + col] = bf16bits(av);
                }
            }
        }
}

// ---------------- GEMM2: zero LDS, zero barriers ----------------
__global__ __launch_bounds__(512, 4) void k_gemm2(
    const unsigned short* __restrict__ act,
    const unsigned short* __restrict__ wt,    // [ne][2880 h][2880 i] bf16 transposed
    const float* __restrict__ bd, const float* __restrict__ topw,
    const int* __restrict__ cnt, const int* __restrict__ offs,
    const int* __restrict__ list, int e0,
    float* __restrict__ out)
{
    const int le = blockIdx.z, e = e0 + le;
    const int lin = blockIdx.x;
    const int l = (lin & 7) * (NB1 / 8) + (lin >> 3);
    const int it = l >> 3, mblk = l & 7;

    const int count = cnt[e];
    const int m0 = mblk * BM;
    if (m0 >= count) return;
    const int mcount = min(BM, count - m0);
    const int h0 = it * BN;
    const int gbase = offs[e] + m0;

    const int tid = threadIdx.x;
    const int lane = tid & 63, wid = tid >> 6;
    const int wm = wid >> 1, wn = wid & 1;
    const int lr = lane & 15, lk = lane >> 4;

    const unsigned short* wtd = wt + (size_t)le * SZ;
    const unsigned short* arow0 = act + (size_t)(gbase + min(wm * 32 + lr, mcount - 1)) * ID;
    const unsigned short* arow1 = act + (size_t)(gbase + min(wm * 32 + 16 + lr, mcount - 1)) * ID;
    const unsigned short* w0 = wtd + (size_t)(h0 + wn * 32 + lr) * ID;
    const unsigned short* w1 = wtd + (size_t)(h0 + wn * 32 + 16 + lr) * ID;

    f32x4 acc[2][2];
#pragma unroll
    for (int mb = 0; mb < 2; mb++)
#pragma unroll
        for (int cb = 0; cb < 2; cb++) acc[mb][cb] = (f32x4){0.f, 0.f, 0.f, 0.f};

#pragma unroll 3
    for (int kt = 0; kt < NKT; kt++) {
        bf16x8 af[2][2], wf[2][2];
#pragma unroll
        for (int ks = 0; ks < 2; ks++) {
            const int koff = kt * 64 + (ks * 4 + lk) * 8;
            af[ks][0] = *(const bf16x8*)(arow0 + koff);
            af[ks][1] = *(const bf16x8*)(arow1 + koff);
            wf[ks][0] = *(const bf16x8*)(w0 + koff);
            wf[ks][1] = *(const bf16x8*)(w1 + koff);
        }
#pragma unroll
        for (int ks = 0; ks < 2; ks++)
#pragma unroll
            for (int cb = 0; cb < 2; cb++) {
                acc[0][cb] = __builtin_amdgcn_mfma_f32_16x16x32_bf16(af[ks][0], wf[ks][cb], acc[0][cb], 0, 0, 0);
                acc[1][cb] = __builtin_amdgcn_mfma_f32_16x16x32_bf16(af[ks][1], wf[ks][cb], acc[1][cb], 0, 0, 0);
            }
    }

#pragma unroll
    for (int mb = 0; mb < 2; mb++)
#pragma unroll
        for (int cb = 0; cb < 2; cb++) {
            const int col = h0 + wn * 32 + cb * 16 + lr;
            const float bdv = bd[e * HD + col];
#pragma unroll
            for (int q = 0; q < 4; q++) {
                const int r = wm * 32 + mb * 16 + lk * 4 + q;
                if (r < mcount) {
                    int idx = list[e * T_TOK + m0 + r];
                    float w = topw[idx];
                    atomicAdd(&out[(size_t)(idx >> 2) * HD + col], w * (acc[mb][cb][q] + bdv));
                }
            }
        }
}

extern "C" void kernel_launch(void* const* d_in, const int* in_sizes, int n_in,
                              void* d_out, int out_size, void* d_ws, size_t ws_size,
                              hipStream_t stream)
{
    const float* x  = (const float*)d_in[0];
    const float* rw = (const float*)d_in[1];
    const float* rb = (const float*)d_in[2];
    const float* wg = (const float*)d_in[3];
    const float* bg = (const float*)d_in[4];
    const float* wu = (const float*)d_in[5];
    const float* bu = (const float*)d_in[6];
    const float* wd = (const float*)d_in[7];
    const float* bd = (const float*)d_in[8];
    float* out = (float*)d_out;

    char* ws = (char*)d_ws;
    int*   cnt  = (int*)(ws + 0);
    int*   offs = (int*)(ws + 256);
    float* topw = (float*)(ws + 1024);
    int*   list = (int*)(ws + 32768);
    unsigned short* act = (unsigned short*)(ws + 131072);                       // 4096x2880 bf16 (23.6 MB)
    unsigned short* xbf = (unsigned short*)(ws + 131072 + (size_t)4096 * ID * 2); // 1024x2880 bf16 (5.9 MB)
    const size_t wtoff = 131072 + (size_t)4096 * ID * 2 + (size_t)T_TOK * HD * 2;
    unsigned short* wt = (unsigned short*)(ws + wtoff);

    const size_t MSb = SZ * 2;   // bf16 matrix bytes (16.6 MB)
    size_t avail = (ws_size > wtoff) ? ws_size - wtoff : 0;
    int ES1 = (int)(avail / (2 * MSb)); if (ES1 < 1) ES1 = 1; if (ES1 > NE) ES1 = NE;
    int ESd = (int)(avail / MSb);       if (ESd < 1) ESd = 1; if (ESd > NE) ESd = NE;

    hipLaunchKernelGGL(k_init, dim3(T_TOK * HD / 1024), dim3(256), 0, stream, out, cnt);
    hipLaunchKernelGGL(k_xbf, dim3(T_TOK * HD / (256 * 8)), dim3(256), 0, stream, x, xbf);
    hipLaunchKernelGGL(k_router, dim3(T_TOK), dim3(256), 0, stream, x, rw, rb, topw, cnt, list);
    hipLaunchKernelGGL(k_scan, dim3(1), dim3(64), 0, stream, cnt, offs);

    for (int e0 = 0; e0 < NE; e0 += ES1) {
        int ne = (NE - e0 < ES1) ? (NE - e0) : ES1;
        hipLaunchKernelGGL(k_trgu, dim3(NIB, NKT, 2 * ne), dim3(256), 0, stream, wg, wu, e0, wt);
        hipLaunchKernelGGL(k_gemm1, dim3(NB1, 1, ne), dim3(512), 0, stream,
                           xbf, wt, bg, bu, cnt, offs, list, e0, act);
    }
    for (int e0 = 0; e0 < NE; e0 += ESd) {
        int ne = (NE - e0 < ESd) ? (NE - e0) : ESd;
        hipLaunchKernelGGL(k_trd, dim3(NIB, NKT, ne), dim3(256), 0, stream, wd, e0, wt);
        hipLaunchKernelGGL(k_gemm2, dim3(NB1, 1, ne), dim3(512), 0, stream,
                           act, wt, bd, topw, cnt, offs, list, e0, out);
    }
}

// Round 6
// 1093.580 us; speedup vs baseline: 2.1059x; 2.1059x over previous
//
#include <hip/hip_runtime.h>
#include <stdint.h>

#define T_TOK 1024
#define HD 2880
#define ID 2880
#define NE 16
#define NTOP 4

#define BM 128
#define BN 64
#define BK 64
#define NKT (HD / BK)         // 45
#define NIB (ID / BN)         // 45
#define NMB (T_TOK / BM)      // 8
#define NBLK (NE * NIB * NMB) // 5760

typedef short bf16x8 __attribute__((ext_vector_type(8)));
typedef float f32x4 __attribute__((ext_vector_type(4)));

__device__ __forceinline__ uint4 pack8f(const float* v) {
    union { __bf16 b[8]; uint4 q; } p;
#pragma unroll
    for (int j = 0; j < 8; j++) p.b[j] = (__bf16)v[j];
    return p.q;
}
__device__ __forceinline__ unsigned short bf16bits(float f) {
    union { __bf16 b[2]; unsigned short u[2]; } p;
    p.b[0] = (__bf16)f;
    return p.u[0];
}

// ---------------- init ----------------
__global__ __launch_bounds__(256) void k_init(float* __restrict__ out, int* __restrict__ cnt) {
    int i = blockIdx.x * 256 + threadIdx.x;
    ((float4*)out)[i] = make_float4(0.f, 0.f, 0.f, 0.f);
    if (blockIdx.x == 0 && threadIdx.x < NE) cnt[threadIdx.x] = 0;
}

// ---------------- x -> bf16 ----------------
__global__ __launch_bounds__(256) void k_xbf(const float* __restrict__ x, unsigned short* __restrict__ xbf) {
    const size_t i = (size_t)blockIdx.x * 256 + threadIdx.x;
    float v[8];
    float4 a = ((const float4*)x)[i * 2];
    float4 b = ((const float4*)x)[i * 2 + 1];
    v[0] = a.x; v[1] = a.y; v[2] = a.z; v[3] = a.w;
    v[4] = b.x; v[5] = b.y; v[6] = b.z; v[7] = b.w;
    ((uint4*)xbf)[i] = pack8f(v);
}

// ---------------- router ----------------
__global__ __launch_bounds__(256) void k_router(
    const float* __restrict__ x, const float* __restrict__ rw, const float* __restrict__ rb,
    float* __restrict__ topw, int* __restrict__ cnt, int* __restrict__ list)
{
    const int t = blockIdx.x;
    const int tid = threadIdx.x;
    float acc[NE];
#pragma unroll
    for (int e = 0; e < NE; e++) acc[e] = 0.f;
    for (int c = tid; c < HD; c += 256) {
        float xv = x[(size_t)t * HD + c];
#pragma unroll
        for (int e = 0; e < NE; e++) acc[e] += xv * rw[(size_t)e * HD + c];
    }
    __shared__ float red[4][NE];
    const int lane = tid & 63, wv = tid >> 6;
#pragma unroll
    for (int e = 0; e < NE; e++) {
        float v = acc[e];
#pragma unroll
        for (int off = 32; off > 0; off >>= 1) v += __shfl_down(v, off, 64);
        if (lane == 0) red[wv][e] = v;
    }
    __syncthreads();
    if (tid == 0) {
        float p[NE];
        float mx = -1e30f;
        for (int e = 0; e < NE; e++) {
            float v = red[0][e] + red[1][e] + red[2][e] + red[3][e] + rb[e];
            p[e] = v; mx = fmaxf(mx, v);
        }
        for (int e = 0; e < NE; e++) p[e] = expf(p[e] - mx);
        int sel[NTOP]; float pw[NTOP]; float ssum = 0.f;
        for (int k = 0; k < NTOP; k++) {
            float best = -1.f; int bi = 0;
            for (int e = 0; e < NE; e++)
                if (p[e] > best) { best = p[e]; bi = e; }
            sel[k] = bi; pw[k] = best; ssum += best; p[bi] = -2.f;
        }
        for (int k = 0; k < NTOP; k++) {
            topw[t * NTOP + k] = pw[k] / ssum;
            int e = sel[k];
            int pos = atomicAdd(&cnt[e], 1);
            list[e * T_TOK + pos] = t * NTOP + k;
        }
    }
}

// ---------------- prefix scan ----------------
__global__ void k_scan(const int* __restrict__ cnt, int* __restrict__ offs) {
    if (threadIdx.x == 0 && blockIdx.x == 0) {
        int s = 0;
        for (int e = 0; e < NE; e++) { offs[e] = s; s += cnt[e]; }
        offs[NE] = s;
    }
}

// ---------------- GEMM1: single-buffered LDS, gload_lds A, cvt_pk W ----------------
__global__ __launch_bounds__(512) void k_gemm1(
    const unsigned short* __restrict__ xbf,
    const float* __restrict__ wg, const float* __restrict__ bg,
    const float* __restrict__ wu, const float* __restrict__ bu,
    const int* __restrict__ cnt, const int* __restrict__ offs,
    const int* __restrict__ list,
    unsigned short* __restrict__ act)
{
    // XCD swizzle: same-panel m-blocks land on one XCD (proven FETCH win)
    const int lin = blockIdx.x;
    const int logical = (lin & 7) * (NBLK / 8) + (lin >> 3);
    const int mblk = logical & 7;
    const int iblk = (logical >> 3) % NIB;
    const int e = logical / (NIB * NMB);

    const int count = cnt[e];
    const int m0 = mblk * BM;
    if (m0 >= count) return;
    const int mcount = min(BM, count - m0);
    const int i0 = iblk * BN;
    const int tid = threadIdx.x;

    __shared__ char sA[BM * BK * 2];   // 16 KB
    __shared__ char sG[BN * BK * 2];   // 8 KB
    __shared__ char sU[BN * BK * 2];   // 8 KB
    __shared__ int lidx[BM];

    if (tid < BM) lidx[tid] = list[e * T_TOK + m0 + min(tid, mcount - 1)];
    __syncthreads();

    const int lane = tid & 63, wid = tid >> 6;
    const int wm = wid >> 1, wn = wid & 1;
    const int lr = lane & 15, lk = lane >> 4;

    // ---- A staging via global_load_lds: LDS linear dest, pre-swizzled global src ----
    // LDS addr of lane l (call c): base(c,w) + l*16  ==> row = c*64 + w*8 + (l>>3), slot = l&7
    // slot s of row r holds col-chunk (s ^ (r&7)); so lane reads chunk (l&7)^((l>>3)&7)
    const int arw0 = wid * 8 + (lane >> 3);
    const int arw1 = 64 + arw0;
    const int asl = ((lane & 7) ^ ((lane >> 3) & 7)) * 8;
    const unsigned short* ga0 = xbf + (size_t)(lidx[arw0] >> 2) * HD + asl;
    const unsigned short* ga1 = xbf + (size_t)(lidx[arw1] >> 2) * HD + asl;
    char* const lb0 = sA + (wid * 8) * 128;
    char* const lb1 = sA + (64 + wid * 8) * 128;

    // ---- W staging: tid<256 gate, else up; 16 coalesced strided floats ----
    const int wtid = tid & 255;
    const int wc = wtid & 63, whg = wtid >> 6;
    const float* wsrc = (tid < 256 ? wg : wu) + ((size_t)e * HD + whg * 16) * ID + i0 + wc;
    char* const wdst = (tid < 256 ? sG : sU);

    f32x4 accG[2][2], accU[2][2];
#pragma unroll
    for (int mb = 0; mb < 2; mb++)
#pragma unroll
        for (int cb = 0; cb < 2; cb++) {
            accG[mb][cb] = (f32x4){0.f, 0.f, 0.f, 0.f};
            accU[mb][cb] = (f32x4){0.f, 0.f, 0.f, 0.f};
        }

    for (int kt = 0; kt < NKT; kt++) {
        // stage A (async DMA, no VGPR roundtrip)
        __builtin_amdgcn_global_load_lds(ga0 + kt * BK, lb0, 16, 0, 0);
        __builtin_amdgcn_global_load_lds(ga1 + kt * BK, lb1, 16, 0, 0);
        // stage W (load + cvt_pk + ds_write)
        {
            float v[16];
#pragma unroll
            for (int j = 0; j < 16; j++) v[j] = wsrc[(size_t)(kt * BK + j) * ID];
            *(uint4*)(wdst + wc * 128 + (((whg * 2) ^ (wc & 7)) * 16)) = pack8f(v);
            *(uint4*)(wdst + wc * 128 + (((whg * 2 + 1) ^ (wc & 7)) * 16)) = pack8f(v + 8);
        }
        __syncthreads();
#pragma unroll
        for (int ks = 0; ks < 2; ks++) {
            const int s = ks * 4 + lk;
            bf16x8 af[2], gf[2], uf[2];
#pragma unroll
            for (int mb = 0; mb < 2; mb++) {
                int rr = wm * 32 + mb * 16 + lr;
                af[mb] = *(const bf16x8*)(sA + rr * 128 + ((s ^ (rr & 7)) * 16));
            }
#pragma unroll
            for (int cb = 0; cb < 2; cb++) {
                int ii = wn * 32 + cb * 16 + lr;
                gf[cb] = *(const bf16x8*)(sG + ii * 128 + ((s ^ (ii & 7)) * 16));
                uf[cb] = *(const bf16x8*)(sU + ii * 128 + ((s ^ (ii & 7)) * 16));
            }
#pragma unroll
            for (int mb = 0; mb < 2; mb++)
#pragma unroll
                for (int cb = 0; cb < 2; cb++) {
                    accG[mb][cb] = __builtin_amdgcn_mfma_f32_16x16x32_bf16(af[mb], gf[cb], accG[mb][cb], 0, 0, 0);
                    accU[mb][cb] = __builtin_amdgcn_mfma_f32_16x16x32_bf16(af[mb], uf[cb], accU[mb][cb], 0, 0, 0);
                }
        }
        __syncthreads();
    }

    const int gbase = offs[e] + m0;
#pragma unroll
    for (int mb = 0; mb < 2; mb++)
#pragma unroll
        for (int cb = 0; cb < 2; cb++) {
            const int col = i0 + wn * 32 + cb * 16 + lr;
            const float bgv = bg[e * ID + col];
            const float buv = bu[e * ID + col];
#pragma unroll
            for (int q = 0; q < 4; q++) {
                const int r = wm * 32 + mb * 16 + lk * 4 + q;
                if (r < mcount) {
                    float gv = fminf(accG[mb][cb][q] + bgv, 7.0f);
                    float uv = fminf(fmaxf(accU[mb][cb][q] + buv, -7.0f), 7.0f);
                    float av = (uv + 1.0f) * (gv / (1.0f + __expf(-1.702f * gv)));
                    act[(size_t)(gbase + r) * ID + col] = bf16bits(av);
                }
            }
        }
}

// ---------------- GEMM2: single-buffered LDS, gload_lds A, cvt_pk W ----------------
__global__ __launch_bounds__(512) void k_gemm2(
    const unsigned short* __restrict__ act,
    const float* __restrict__ wd, const float* __restrict__ bd,
    const float* __restrict__ topw,
    const int* __restrict__ cnt, const int* __restrict__ offs,
    const int* __restrict__ list,
    float* __restrict__ out)
{
    const int lin = blockIdx.x;
    const int logical = (lin & 7) * (NBLK / 8) + (lin >> 3);
    const int mblk = logical & 7;
    const int hblk = (logical >> 3) % NIB;
    const int e = logical / (NIB * NMB);

    const int count = cnt[e];
    const int m0 = mblk * BM;
    if (m0 >= count) return;
    const int mcount = min(BM, count - m0);
    const int h0 = hblk * BN;
    const int tid = threadIdx.x;
    const int gbase = offs[e] + m0;

    __shared__ char sA[BM * BK * 2];   // 16 KB
    __shared__ char sW[BN * BK * 2];   // 8 KB
    __shared__ int lidx[BM];

    if (tid < BM) lidx[tid] = list[e * T_TOK + m0 + min(tid, mcount - 1)];
    __syncthreads();

    const int lane = tid & 63, wid = tid >> 6;
    const int wm = wid >> 1, wn = wid & 1;
    const int lr = lane & 15, lk = lane >> 4;

    const int arw0 = wid * 8 + (lane >> 3);
    const int arw1 = 64 + arw0;
    const int asl = ((lane & 7) ^ ((lane >> 3) & 7)) * 8;
    const unsigned short* ga0 = act + (size_t)(gbase + min(arw0, mcount - 1)) * ID + asl;
    const unsigned short* ga1 = act + (size_t)(gbase + min(arw1, mcount - 1)) * ID + asl;
    char* const lb0 = sA + (wid * 8) * 128;
    char* const lb1 = sA + (64 + wid * 8) * 128;

    const int wc = tid & 63, whg = tid >> 6;   // 8 k-groups of 8
    const float* wsrc = wd + (size_t)e * ID * HD + (size_t)(whg * 8) * HD + h0 + wc;

    f32x4 acc[2][2];
#pragma unroll
    for (int mb = 0; mb < 2; mb++)
#pragma unroll
        for (int cb = 0; cb < 2; cb++) acc[mb][cb] = (f32x4){0.f, 0.f, 0.f, 0.f};

    for (int kt = 0; kt < NKT; kt++) {
        __builtin_amdgcn_global_load_lds(ga0 + kt * BK, lb0, 16, 0, 0);
        __builtin_amdgcn_global_load_lds(ga1 + kt * BK, lb1, 16, 0, 0);
        {
            float v[8];
#pragma unroll
            for (int j = 0; j < 8; j++) v[j] = wsrc[(size_t)(kt * BK + j) * HD];
            *(uint4*)(sW + wc * 128 + ((whg ^ (wc & 7)) * 16)) = pack8f(v);
        }
        __syncthreads();
#pragma unroll
        for (int ks = 0; ks < 2; ks++) {
            const int s = ks * 4 + lk;
            bf16x8 af[2], wf[2];
#pragma unroll
            for (int mb = 0; mb < 2; mb++) {
                int rr = wm * 32 + mb * 16 + lr;
                af[mb] = *(const bf16x8*)(sA + rr * 128 + ((s ^ (rr & 7)) * 16));
            }
#pragma unroll
            for (int cb = 0; cb < 2; cb++) {
                int ii = wn * 32 + cb * 16 + lr;
                wf[cb] = *(const bf16x8*)(sW + ii * 128 + ((s ^ (ii & 7)) * 16));
            }
#pragma unroll
            for (int mb = 0; mb < 2; mb++)
#pragma unroll
                for (int cb = 0; cb < 2; cb++)
                    acc[mb][cb] = __builtin_amdgcn_mfma_f32_16x16x32_bf16(af[mb], wf[cb], acc[mb][cb], 0, 0, 0);
        }
        __syncthreads();
    }

#pragma unroll
    for (int mb = 0; mb < 2; mb++)
#pragma unroll
        for (int cb = 0; cb < 2; cb++) {
            const int col = h0 + wn * 32 + cb * 16 + lr;
            const float bdv = bd[e * HD + col];
#pragma unroll
            for (int q = 0; q < 4; q++) {
                const int r = wm * 32 + mb * 16 + lk * 4 + q;
                if (r < mcount) {
                    int idx = lidx[r];
                    float w = topw[idx];
                    atomicAdd(&out[(size_t)(idx >> 2) * HD + col], w * (acc[mb][cb][q] + bdv));
                }
            }
        }
}

extern "C" void kernel_launch(void* const* d_in, const int* in_sizes, int n_in,
                              void* d_out, int out_size, void* d_ws, size_t ws_size,
                              hipStream_t stream)
{
    const float* x  = (const float*)d_in[0];
    const float* rw = (const float*)d_in[1];
    const float* rb = (const float*)d_in[2];
    const float* wg = (const float*)d_in[3];
    const float* bg = (const float*)d_in[4];
    const float* wu = (const float*)d_in[5];
    const float* bu = (const float*)d_in[6];
    const float* wd = (const float*)d_in[7];
    const float* bd = (const float*)d_in[8];
    float* out = (float*)d_out;

    char* ws = (char*)d_ws;
    int*   cnt  = (int*)(ws + 0);
    int*   offs = (int*)(ws + 256);
    float* topw = (float*)(ws + 1024);
    int*   list = (int*)(ws + 32768);
    unsigned short* act = (unsigned short*)(ws + 131072);                         // 4096x2880 bf16
    unsigned short* xbf = (unsigned short*)(ws + 131072 + (size_t)4096 * ID * 2); // 1024x2880 bf16

    hipLaunchKernelGGL(k_init, dim3(T_TOK * HD / 1024), dim3(256), 0, stream, out, cnt);
    hipLaunchKernelGGL(k_xbf, dim3(T_TOK * HD / (256 * 8)), dim3(256), 0, stream, x, xbf);
    hipLaunchKernelGGL(k_router, dim3(T_TOK), dim3(256), 0, stream, x, rw, rb, topw, cnt, list);
    hipLaunchKernelGGL(k_scan, dim3(1), dim3(64), 0, stream, cnt, offs);
    hipLaunchKernelGGL(k_gemm1, dim3(NBLK), dim3(512), 0, stream,
                       xbf, wg, bg, wu, bu, cnt, offs, list, act);
    hipLaunchKernelGGL(k_gemm2, dim3(NBLK), dim3(512), 0, stream,
                       act, wd, bd, topw, cnt, offs, list, out);
}